// Round 6
// baseline (664.376 us; speedup 1.0000x reference)
//
#include <hip/hip_runtime.h>
#include <hip/hip_bf16.h>
#include <stdint.h>

typedef short short8 __attribute__((ext_vector_type(8)));
typedef float f32x4  __attribute__((ext_vector_type(4)));

typedef __attribute__((address_space(1))) uint32_t u32_g;
typedef __attribute__((address_space(3))) uint32_t u32_l;

#define BM 128
#define BN 128
#define BK 64

// async global->LDS, 16 bytes per lane. LDS dest must be wave-uniform base +
// lane*16 contiguous (generic LDS pointer low 32 bits == LDS offset on amdgcn).
__device__ __forceinline__ void gld_lds16(const void* g, const void* l) {
  __builtin_amdgcn_global_load_lds((u32_g*)(uintptr_t)g, (u32_l*)(uintptr_t)l, 16, 0, 0);
}

// XCD-chunked serpentine block swizzle (bijective when nwg % 8 == 0).
// Each XCD (bid&7) gets a contiguous chunk of a virtual order that walks
// 2-wide bn strips with bm interleaved: its ~2 B-panels stay L2-resident,
// and all XCDs stream A-panels near-lockstep (L3 serves A once).
__device__ __forceinline__ void swz_block(int& tm, int& tn) {
  const int gx  = gridDim.x, gy = gridDim.y;
  const int bid = blockIdx.y * gx + blockIdx.x;
  const int nwg = gx * gy;
  const int chunk = nwg >> 3;
  const int v = (bid & 7) * chunk + (bid >> 3);
  const int strip = v / (2 * gx);
  const int rem   = v % (2 * gx);
  const int b0 = strip * 2;
  if (b0 + 1 < gy) { tm = rem >> 1; tn = b0 + (rem & 1); }
  else             { tm = rem;      tn = b0; }           // odd tail strip
}

// ---------------------------------------------------------------------------
// GEMM: C = epilogue(A[M,K](bf16) @ BT[N,K](bf16)^T + bias(fp32))
// m97-structure 128x128 tile (verified 99us/GEMM here; ~3-5 blocks/CU TLP).
// FINAL=0: leaky-relu, store bf16 to Cb (stride 2048)
// FINAL=1: diag-abs + triangle scatter, store fp32: Cf[(r*64+c)*8192 + m],
//          plus zero-store to mirrored lower-triangle slot (replaces memset)
// ---------------------------------------------------------------------------
template <int FINAL>
__global__ __launch_bounds__(256) void gemm_k(
    const __hip_bfloat16* __restrict__ A,
    const __hip_bfloat16* __restrict__ BT,
    const float* __restrict__ bias,
    __hip_bfloat16* __restrict__ Cb,
    float* __restrict__ Cf,
    const int* __restrict__ tbl,
    int K, int Nreal)
{
  __shared__ __attribute__((aligned(16))) __hip_bfloat16 As[BM * BK];
  __shared__ __attribute__((aligned(16))) __hip_bfloat16 Bs[BN * BK];

  const int tid  = threadIdx.x;
  const int lane = tid & 63;
  const int l15  = lane & 15;
  const int quad = lane >> 4;
  const int wave = tid >> 6;
  const int wm   = (wave >> 1) << 6;   // wave row offset within 128-tile
  const int wn   = (wave & 1) << 6;    // wave col offset

  int tm, tn;
  swz_block(tm, tn);
  const int bm = tm * BM;
  const int bn = tn * BN;

  // Staging: tile rows are 64 bf16 = 8 chunks of 16B. chunk ci = tid + 256*c.
  // XOR-swizzle the chunk on the GLOBAL side so LDS stays wave-contiguous
  // (global_load_lds constraint) while fragment reads (128B stride) spread
  // across banks.
  const __hip_bfloat16* ag[4];
  const __hip_bfloat16* bg[4];
  uint32_t lofs[4];
#pragma unroll
  for (int c = 0; c < 4; ++c) {
    int ci   = tid + 256 * c;        // 0..1023
    int row  = ci >> 3;              // 0..127
    int chk  = ci & 7;
    int gchk = chk ^ (row & 7);
    ag[c]   = A  + (size_t)(bm + row) * K + gchk * 8;
    bg[c]   = BT + (size_t)(bn + row) * K + gchk * 8;
    lofs[c] = (uint32_t)ci * 16u;
  }

  f32x4 acc[4][4];
#pragma unroll
  for (int i = 0; i < 4; ++i)
#pragma unroll
    for (int j = 0; j < 4; ++j)
      acc[i][j] = (f32x4){0.f, 0.f, 0.f, 0.f};

  const int nk = K >> 6;
  for (int kt = 0; kt < nk; ++kt) {
#pragma unroll
    for (int c = 0; c < 4; ++c) {
      gld_lds16(ag[c], (const char*)As + lofs[c]);
      gld_lds16(bg[c], (const char*)Bs + lofs[c]);
      ag[c] += BK;
      bg[c] += BK;
    }
    __syncthreads();   // drains vmcnt(0) -> LDS tiles complete
#pragma unroll
    for (int ks = 0; ks < 2; ++ks) {
      short8 af[4], bf[4];
      const int cf = ks * 4 + quad;  // 8-elem k-chunk of the 64-wide row
#pragma unroll
      for (int i = 0; i < 4; ++i) {
        int m  = wm + i * 16 + l15;
        int sc = cf ^ (m & 7);
        af[i]  = *(const short8*)(As + m * BK + sc * 8);
      }
#pragma unroll
      for (int j = 0; j < 4; ++j) {
        int n  = wn + j * 16 + l15;
        int sc = cf ^ (n & 7);
        bf[j]  = *(const short8*)(Bs + n * BK + sc * 8);
      }
#pragma unroll
      for (int i = 0; i < 4; ++i)
#pragma unroll
        for (int j = 0; j < 4; ++j)
          acc[i][j] = __builtin_amdgcn_mfma_f32_16x16x32_bf16(af[i], bf[j], acc[i][j], 0, 0, 0);
    }
    __syncthreads();   // protect LDS from next tile's staging
  }

  // Epilogue. C/D layout: col = lane&15, row = quad*4 + reg (m89-verified).
  if (FINAL == 0) {
#pragma unroll
    for (int j = 0; j < 4; ++j) {
      int   n  = bn + wn + j * 16 + l15;
      float bv = bias[n];
#pragma unroll
      for (int i = 0; i < 4; ++i) {
        int m0 = bm + wm + i * 16 + quad * 4;
#pragma unroll
        for (int r = 0; r < 4; ++r) {
          float v = acc[i][j][r] + bv;
          v = (v > 0.f) ? v : 0.01f * v;
          Cb[(size_t)(m0 + r) * 2048 + n] = __float2bfloat16(v);
        }
      }
    }
  } else {
#pragma unroll
    for (int j = 0; j < 4; ++j) {
      int n = bn + wn + j * 16 + l15;
      if (n < Nreal) {
        float bv   = bias[n];
        int  code  = tbl[n];
        int  dst   = code & 4095;          // r*64 + c (upper triangle)
        bool diag  = (code & 4096) != 0;
        int  mir   = ((dst & 63) << 6) | (dst >> 6);  // (c,r) lower mirror
        const f32x4 z = (f32x4){0.f, 0.f, 0.f, 0.f};
#pragma unroll
        for (int i = 0; i < 4; ++i) {
          int m0 = bm + wm + i * 16 + quad * 4;
          f32x4 pk;
#pragma unroll
          for (int r = 0; r < 4; ++r) {
            float v = acc[i][j][r] + bv;
            if (diag) v = fabsf(v);
            pk[r] = v;
          }
          // 4 consecutive batch rows at one (r,c): aligned 16B store
          *reinterpret_cast<f32x4*>(Cf + (size_t)dst * 8192 + m0) = pk;
          if (!diag)  // strict-upper (r,c) <-> strict-lower (c,r) bijection
            *reinterpret_cast<f32x4*>(Cf + (size_t)mir * 8192 + m0) = z;
        }
      }
    }
  }
}

// ---------------------------------------------------------------------------
// Weight transpose + fp32->bf16: in[K,N](f32) -> out[NP,K](bf16), rows >= N zero
// ---------------------------------------------------------------------------
__global__ void transpose_k(const float* __restrict__ in,
                            __hip_bfloat16* __restrict__ out,
                            int K, int N)
{
  __shared__ __hip_bfloat16 t[32][33];
  const int n0 = blockIdx.x * 32;
  const int k0 = blockIdx.y * 32;
  const int tx = threadIdx.x, ty = threadIdx.y;
  const __hip_bfloat16 zero = __float2bfloat16(0.f);
#pragma unroll
  for (int r = 0; r < 32; r += 8) {
    int k = k0 + ty + r, n = n0 + tx;
    t[ty + r][tx] = (n < N) ? __float2bfloat16(in[(size_t)k * N + n]) : zero;
  }
  __syncthreads();
#pragma unroll
  for (int r = 0; r < 32; r += 8) {
    int n = n0 + ty + r;
    out[(size_t)n * K + k0 + tx] = t[tx][ty + r];
  }
}

// fp32 -> bf16 elementwise (x), 4 per thread
__global__ void cvt_k(const float* __restrict__ in,
                      __hip_bfloat16* __restrict__ out, int n)
{
  int i = (blockIdx.x * 256 + threadIdx.x) * 4;
  if (i >= n) return;
  float4 v = *reinterpret_cast<const float4*>(in + i);
  union { unsigned short us[4]; uint2 v2; } pk;
  __hip_bfloat16 h;
  h = __float2bfloat16(v.x); pk.us[0] = *reinterpret_cast<unsigned short*>(&h);
  h = __float2bfloat16(v.y); pk.us[1] = *reinterpret_cast<unsigned short*>(&h);
  h = __float2bfloat16(v.z); pk.us[2] = *reinterpret_cast<unsigned short*>(&h);
  h = __float2bfloat16(v.w); pk.us[3] = *reinterpret_cast<unsigned short*>(&h);
  *reinterpret_cast<uint2*>(out + i) = pk.v2;
}

// l -> (r,c) scatter table. Row r covers cols 63..r; diag (c==r) flagged bit 12.
__global__ void table_k(int* __restrict__ tbl)
{
  int l = blockIdx.x * 64 + threadIdx.x;
  if (l >= 2080) return;
  int r = 0, s = 0;
  while (s + (64 - r) <= l) { s += 64 - r; ++r; }
  int c = 63 - (l - s);
  tbl[l] = (r * 64 + c) | ((r == c) ? 4096 : 0);
}

extern "C" void kernel_launch(void* const* d_in, const int* in_sizes, int n_in,
                              void* d_out, int out_size, void* d_ws, size_t ws_size,
                              hipStream_t stream)
{
  const float* x   = (const float*)d_in[0];
  const float* W1  = (const float*)d_in[1];
  const float* b1  = (const float*)d_in[2];
  const float* W2  = (const float*)d_in[3];
  const float* b2  = (const float*)d_in[4];
  const float* W21 = (const float*)d_in[5];
  const float* b21 = (const float*)d_in[6];
  const float* W22 = (const float*)d_in[7];
  const float* b22 = (const float*)d_in[8];
  const float* W3  = (const float*)d_in[9];
  const float* b3  = (const float*)d_in[10];
  float* out = (float*)d_out;

  char* ws = (char*)d_ws;
  __hip_bfloat16* act0 = (__hip_bfloat16*)(ws);                         // 8192x2048 bf16
  __hip_bfloat16* act1 = (__hip_bfloat16*)(ws + ((size_t)32 << 20));    // 8192x2048 bf16
  __hip_bfloat16* xb   = act1;                                          // 8192x1024 bf16 (dead after GEMM1)
  __hip_bfloat16* W1T  = (__hip_bfloat16*)(ws + ((size_t)64 << 20));    // 2048x1024
  __hip_bfloat16* W2T  = (__hip_bfloat16*)(ws + ((size_t)68 << 20));    // 2048x2048
  __hip_bfloat16* W21T = (__hip_bfloat16*)(ws + ((size_t)76 << 20));    // 2048x2048
  __hip_bfloat16* W22T = (__hip_bfloat16*)(ws + ((size_t)84 << 20));    // 2048x2048
  __hip_bfloat16* W3T  = (__hip_bfloat16*)(ws + ((size_t)92 << 20));    // 2176x2048 (zero-padded)
  int*            tbl  = (int*)(ws + ((size_t)101 << 20));              // 2080 ints

  // No output memset: FINAL gemm writes upper triangle + mirrored zeros.
  table_k<<<33, 64, 0, stream>>>(tbl);

  cvt_k<<<8192, 256, 0, stream>>>(x, xb, 8192 * 1024);

  dim3 tb(32, 8);
  transpose_k<<<dim3(64, 32), tb, 0, stream>>>(W1,  W1T,  1024, 2048);
  transpose_k<<<dim3(64, 64), tb, 0, stream>>>(W2,  W2T,  2048, 2048);
  transpose_k<<<dim3(64, 64), tb, 0, stream>>>(W21, W21T, 2048, 2048);
  transpose_k<<<dim3(64, 64), tb, 0, stream>>>(W22, W22T, 2048, 2048);
  transpose_k<<<dim3(68, 64), tb, 0, stream>>>(W3,  W3T,  2048, 2080); // rows 2080..2175 zero

  gemm_k<0><<<dim3(64, 16), 256, 0, stream>>>(xb,   W1T,  b1,  act0, nullptr, nullptr, 1024, 2048);
  gemm_k<0><<<dim3(64, 16), 256, 0, stream>>>(act0, W2T,  b2,  act1, nullptr, nullptr, 2048, 2048);
  gemm_k<0><<<dim3(64, 16), 256, 0, stream>>>(act1, W21T, b21, act0, nullptr, nullptr, 2048, 2048);
  gemm_k<0><<<dim3(64, 16), 256, 0, stream>>>(act0, W22T, b22, act1, nullptr, nullptr, 2048, 2048);
  gemm_k<1><<<dim3(64, 17), 256, 0, stream>>>(act1, W3T,  b3,  nullptr, out,  tbl,     2048, 2080);
}

// Round 7
// 561.539 us; speedup vs baseline: 1.1831x; 1.1831x over previous
//
#include <hip/hip_runtime.h>
#include <hip/hip_bf16.h>
#include <stdint.h>

typedef short short8 __attribute__((ext_vector_type(8)));
typedef float f32x4  __attribute__((ext_vector_type(4)));

typedef __attribute__((address_space(1))) uint32_t u32_g;
typedef __attribute__((address_space(3))) uint32_t u32_l;

#define BM 128
#define BN 128
#define BK 64

// async global->LDS, 16 bytes per lane. LDS dest must be wave-uniform base +
// lane*16 contiguous (generic LDS pointer low 32 bits == LDS offset on amdgcn).
__device__ __forceinline__ void gld_lds16(const void* g, const void* l) {
  __builtin_amdgcn_global_load_lds((u32_g*)(uintptr_t)g, (u32_l*)(uintptr_t)l, 16, 0, 0);
}

// ---------------------------------------------------------------------------
// GEMM: C = epilogue(A[M,K](bf16) @ BT[N,K](bf16)^T + bias(fp32))
// m97 structure + classic LDS double-buffer, ONE __syncthreads per K-step:
//   step k: issue stage(k+1 -> other buf); ds_read+MFMA on cur buf; sync.
// The sync's vmcnt(0) drain now targets a DMA issued ~2000 cycles earlier
// (hidden), instead of a just-issued one (the m97 ~20% stall).
// r4 established the compiler does NOT insert its own vmcnt(0) before the
// ds_reads, so plain C++ reads are safe here.
// FINAL=0: leaky-relu, store bf16 to Cb (stride 2048); store order i,r-outer /
//          j-inner so each 128B line is completed by 4 consecutive stores
//          (fixes the 2x write amplification seen as WRITE 66.5 vs 33.5 MB).
// FINAL=1: diag-abs + triangle scatter, fp32 Cf[(r*64+c)*8192 + m], plus
//          zero-store to mirrored lower-triangle slot (replaces memset).
// ---------------------------------------------------------------------------
template <int FINAL>
__global__ __launch_bounds__(256) void gemm_k(
    const __hip_bfloat16* __restrict__ A,
    const __hip_bfloat16* __restrict__ BT,
    const float* __restrict__ bias,
    __hip_bfloat16* __restrict__ Cb,
    float* __restrict__ Cf,
    const int* __restrict__ tbl,
    int K, int Nreal)
{
  // dbuf arena: buf b at b*32768; A at +0 (16K), B at +16384 (16K).
  __shared__ __attribute__((aligned(16))) char smem[65536];

  const int tid  = threadIdx.x;
  const int lane = tid & 63;
  const int l15  = lane & 15;
  const int quad = lane >> 4;
  const int wave = tid >> 6;
  const int wm   = (wave >> 1) << 6;   // wave row offset within 128-tile
  const int wn   = (wave & 1) << 6;    // wave col offset

  const int bm = blockIdx.x * BM;
  const int bn = blockIdx.y * BN;

  // Staging: tile rows are 64 bf16 = 8 chunks of 16B. chunk ci = tid + 256*c.
  // XOR-swizzle the chunk on the GLOBAL side so LDS stays wave-contiguous
  // (global_load_lds constraint) while fragment reads (128B stride) spread
  // across banks.
  const __hip_bfloat16* ag[4];
  const __hip_bfloat16* bg[4];
  uint32_t lofs[4];
#pragma unroll
  for (int c = 0; c < 4; ++c) {
    int ci   = tid + 256 * c;        // 0..1023
    int row  = ci >> 3;              // 0..127
    int chk  = ci & 7;
    int gchk = chk ^ (row & 7);
    ag[c]   = A  + (size_t)(bm + row) * K + gchk * 8;
    bg[c]   = BT + (size_t)(bn + row) * K + gchk * 8;
    lofs[c] = (uint32_t)ci * 16u;
  }

  f32x4 acc[4][4];
#pragma unroll
  for (int i = 0; i < 4; ++i)
#pragma unroll
    for (int j = 0; j < 4; ++j)
      acc[i][j] = (f32x4){0.f, 0.f, 0.f, 0.f};

  const int nk = K >> 6;

  // prologue: stage tile 0 into buf0, drain at the sync
#pragma unroll
  for (int c = 0; c < 4; ++c) {
    gld_lds16(ag[c], smem + lofs[c]);
    gld_lds16(bg[c], smem + 16384 + lofs[c]);
    ag[c] += BK;
    bg[c] += BK;
  }
  __syncthreads();

  for (int kt = 0; kt < nk; ++kt) {
    const char* rb = smem + (kt & 1) * 32768;
    char*       sb = smem + ((kt + 1) & 1) * 32768;

    // issue next tile's staging FIRST -- latency hides under this step's MFMA
    if (kt + 1 < nk) {
#pragma unroll
      for (int c = 0; c < 4; ++c) {
        gld_lds16(ag[c], sb + lofs[c]);
        gld_lds16(bg[c], sb + 16384 + lofs[c]);
        ag[c] += BK;
        bg[c] += BK;
      }
    }

#pragma unroll
    for (int ks = 0; ks < 2; ++ks) {
      short8 af[4], bf[4];
      const int cf = ks * 4 + quad;  // 8-elem k-chunk of the 64-wide row
#pragma unroll
      for (int i = 0; i < 4; ++i) {
        int m  = wm + i * 16 + l15;
        int sc = cf ^ (m & 7);
        af[i]  = *(const short8*)(rb + m * 128 + sc * 16);
      }
#pragma unroll
      for (int j = 0; j < 4; ++j) {
        int n  = wn + j * 16 + l15;
        int sc = cf ^ (n & 7);
        bf[j]  = *(const short8*)(rb + 16384 + n * 128 + sc * 16);
      }
#pragma unroll
      for (int i = 0; i < 4; ++i)
#pragma unroll
        for (int j = 0; j < 4; ++j)
          acc[i][j] = __builtin_amdgcn_mfma_f32_16x16x32_bf16(af[i], bf[j], acc[i][j], 0, 0, 0);
    }
    // single barrier: (a) vmcnt(0) drain of stage(kt+1) -- issued ~2000cyc
    // ago, hidden; (b) all waves done reading rb before it's restaged next step.
    __syncthreads();
  }

  // Epilogue. C/D layout: col = lane&15, row = quad*4 + reg (m89-verified).
  if (FINAL == 0) {
    float bv[4];
#pragma unroll
    for (int j = 0; j < 4; ++j) bv[j] = bias[bn + wn + j * 16 + l15];
#pragma unroll
    for (int i = 0; i < 4; ++i) {
#pragma unroll
      for (int r = 0; r < 4; ++r) {
        const size_t rowoff = (size_t)(bm + wm + i * 16 + quad * 4 + r) * 2048;
#pragma unroll
        for (int j = 0; j < 4; ++j) {   // 4 consecutive 32B store bursts -> full 128B line
          int n = bn + wn + j * 16 + l15;
          float v = acc[i][j][r] + bv[j];
          v = (v > 0.f) ? v : 0.01f * v;
          Cb[rowoff + n] = __float2bfloat16(v);
        }
      }
    }
  } else {
#pragma unroll
    for (int j = 0; j < 4; ++j) {
      int n = bn + wn + j * 16 + l15;
      if (n < Nreal) {
        float bv   = bias[n];
        int  code  = tbl[n];
        int  dst   = code & 4095;          // r*64 + c (upper triangle)
        bool diag  = (code & 4096) != 0;
        int  mir   = ((dst & 63) << 6) | (dst >> 6);  // (c,r) lower mirror
        const f32x4 z = (f32x4){0.f, 0.f, 0.f, 0.f};
#pragma unroll
        for (int i = 0; i < 4; ++i) {
          int m0 = bm + wm + i * 16 + quad * 4;
          f32x4 pk;
#pragma unroll
          for (int r = 0; r < 4; ++r) {
            float v = acc[i][j][r] + bv;
            if (diag) v = fabsf(v);
            pk[r] = v;
          }
          // 4 consecutive batch rows at one (r,c): aligned 16B store
          *reinterpret_cast<f32x4*>(Cf + (size_t)dst * 8192 + m0) = pk;
          if (!diag)  // strict-upper (r,c) <-> strict-lower (c,r) bijection
            *reinterpret_cast<f32x4*>(Cf + (size_t)mir * 8192 + m0) = z;
        }
      }
    }
  }
}

// ---------------------------------------------------------------------------
// Weight transpose + fp32->bf16: in[K,N](f32) -> out[NP,K](bf16), rows >= N zero
// ---------------------------------------------------------------------------
__global__ void transpose_k(const float* __restrict__ in,
                            __hip_bfloat16* __restrict__ out,
                            int K, int N)
{
  __shared__ __hip_bfloat16 t[32][33];
  const int n0 = blockIdx.x * 32;
  const int k0 = blockIdx.y * 32;
  const int tx = threadIdx.x, ty = threadIdx.y;
  const __hip_bfloat16 zero = __float2bfloat16(0.f);
#pragma unroll
  for (int r = 0; r < 32; r += 8) {
    int k = k0 + ty + r, n = n0 + tx;
    t[ty + r][tx] = (n < N) ? __float2bfloat16(in[(size_t)k * N + n]) : zero;
  }
  __syncthreads();
#pragma unroll
  for (int r = 0; r < 32; r += 8) {
    int n = n0 + ty + r;
    out[(size_t)n * K + k0 + tx] = t[tx][ty + r];
  }
}

// fp32 -> bf16 elementwise (x), 4 per thread
__global__ void cvt_k(const float* __restrict__ in,
                      __hip_bfloat16* __restrict__ out, int n)
{
  int i = (blockIdx.x * 256 + threadIdx.x) * 4;
  if (i >= n) return;
  float4 v = *reinterpret_cast<const float4*>(in + i);
  union { unsigned short us[4]; uint2 v2; } pk;
  __hip_bfloat16 h;
  h = __float2bfloat16(v.x); pk.us[0] = *reinterpret_cast<unsigned short*>(&h);
  h = __float2bfloat16(v.y); pk.us[1] = *reinterpret_cast<unsigned short*>(&h);
  h = __float2bfloat16(v.z); pk.us[2] = *reinterpret_cast<unsigned short*>(&h);
  h = __float2bfloat16(v.w); pk.us[3] = *reinterpret_cast<unsigned short*>(&h);
  *reinterpret_cast<uint2*>(out + i) = pk.v2;
}

// l -> (r,c) scatter table. Row r covers cols 63..r; diag (c==r) flagged bit 12.
__global__ void table_k(int* __restrict__ tbl)
{
  int l = blockIdx.x * 64 + threadIdx.x;
  if (l >= 2080) return;
  int r = 0, s = 0;
  while (s + (64 - r) <= l) { s += 64 - r; ++r; }
  int c = 63 - (l - s);
  tbl[l] = (r * 64 + c) | ((r == c) ? 4096 : 0);
}

extern "C" void kernel_launch(void* const* d_in, const int* in_sizes, int n_in,
                              void* d_out, int out_size, void* d_ws, size_t ws_size,
                              hipStream_t stream)
{
  const float* x   = (const float*)d_in[0];
  const float* W1  = (const float*)d_in[1];
  const float* b1  = (const float*)d_in[2];
  const float* W2  = (const float*)d_in[3];
  const float* b2  = (const float*)d_in[4];
  const float* W21 = (const float*)d_in[5];
  const float* b21 = (const float*)d_in[6];
  const float* W22 = (const float*)d_in[7];
  const float* b22 = (const float*)d_in[8];
  const float* W3  = (const float*)d_in[9];
  const float* b3  = (const float*)d_in[10];
  float* out = (float*)d_out;

  char* ws = (char*)d_ws;
  __hip_bfloat16* act0 = (__hip_bfloat16*)(ws);                         // 8192x2048 bf16
  __hip_bfloat16* act1 = (__hip_bfloat16*)(ws + ((size_t)32 << 20));    // 8192x2048 bf16
  __hip_bfloat16* xb   = act1;                                          // 8192x1024 bf16 (dead after GEMM1)
  __hip_bfloat16* W1T  = (__hip_bfloat16*)(ws + ((size_t)64 << 20));    // 2048x1024
  __hip_bfloat16* W2T  = (__hip_bfloat16*)(ws + ((size_t)68 << 20));    // 2048x2048
  __hip_bfloat16* W21T = (__hip_bfloat16*)(ws + ((size_t)76 << 20));    // 2048x2048
  __hip_bfloat16* W22T = (__hip_bfloat16*)(ws + ((size_t)84 << 20));    // 2048x2048
  __hip_bfloat16* W3T  = (__hip_bfloat16*)(ws + ((size_t)92 << 20));    // 2176x2048 (zero-padded)
  int*            tbl  = (int*)(ws + ((size_t)101 << 20));              // 2080 ints

  // No output memset: FINAL gemm writes upper triangle + mirrored zeros.
  table_k<<<33, 64, 0, stream>>>(tbl);

  cvt_k<<<8192, 256, 0, stream>>>(x, xb, 8192 * 1024);

  dim3 tb(32, 8);
  transpose_k<<<dim3(64, 32), tb, 0, stream>>>(W1,  W1T,  1024, 2048);
  transpose_k<<<dim3(64, 64), tb, 0, stream>>>(W2,  W2T,  2048, 2048);
  transpose_k<<<dim3(64, 64), tb, 0, stream>>>(W21, W21T, 2048, 2048);
  transpose_k<<<dim3(64, 64), tb, 0, stream>>>(W22, W22T, 2048, 2048);
  transpose_k<<<dim3(68, 64), tb, 0, stream>>>(W3,  W3T,  2048, 2080); // rows 2080..2175 zero

  gemm_k<0><<<dim3(64, 16), 256, 0, stream>>>(xb,   W1T,  b1,  act0, nullptr, nullptr, 1024, 2048);
  gemm_k<0><<<dim3(64, 16), 256, 0, stream>>>(act0, W2T,  b2,  act1, nullptr, nullptr, 2048, 2048);
  gemm_k<0><<<dim3(64, 16), 256, 0, stream>>>(act1, W21T, b21, act0, nullptr, nullptr, 2048, 2048);
  gemm_k<0><<<dim3(64, 16), 256, 0, stream>>>(act0, W22T, b22, act1, nullptr, nullptr, 2048, 2048);
  gemm_k<1><<<dim3(64, 17), 256, 0, stream>>>(act1, W3T,  b3,  nullptr, out,  tbl,     2048, 2080);
}